// Round 1
// baseline (806.527 us; speedup 1.0000x reference)
//
#include <hip/hip_runtime.h>
#include <hip/hip_bf16.h>
#include <stdint.h>

// ---------------------------------------------------------------------------
// GQA per-token head-mixing attention, MI355X (gfx950)
//   q = x@Wq^T, k = x@Wk^T, v = x@Wv^T   (fused as one GEMM vs [Wq;Wk;Wv])
//   RoPE(q), RoPE(k); q-head permutation h_old = ((h&3)<<2)|(h>>2)
//   scores[h][t] = q[h]·k[t]/sqrt(128) per token, softmax over t (16 heads)
//   attn[h] = sum_t p[h][t] v[t];  out = attn @ Wo^T (f32)
// Workspace layout (needs 288 MiB):
//   [0)                xb   : M*D bf16 (64 MiB)  -- reused as attn buffer
//   [64 MiB)           wqkv : 3*D*D bf16 (24 MiB)
//   [88 MiB)           wo   : D*D bf16 (8 MiB)
//   [96 MiB)           qkv  : M*3D bf16 (192 MiB)
// ---------------------------------------------------------------------------

typedef __attribute__((ext_vector_type(8))) short short8;
typedef __attribute__((ext_vector_type(4))) float f32x4;
typedef uint16_t u16;

typedef __attribute__((address_space(1))) const void as1_const_void;
typedef __attribute__((address_space(3))) void as3_void;
#define GLD_LDS16(gp, lp)                                                     \
  __builtin_amdgcn_global_load_lds((as1_const_void*)(gp), (as3_void*)(lp),    \
                                   16, 0, 0)

__device__ __forceinline__ float bf2f(u16 u) {
  uint32_t x = ((uint32_t)u) << 16;
  float f;
  __builtin_memcpy(&f, &x, 4);
  return f;
}
__device__ __forceinline__ u16 f2bf(float f) {
  uint32_t u;
  __builtin_memcpy(&u, &f, 4);
  u += 0x7fffu + ((u >> 16) & 1u);  // round-to-nearest-even
  return (u16)(u >> 16);
}

// ---------------- f32 -> bf16 convert, 4 elems/thread ----------------------
__global__ __launch_bounds__(256) void cvt_f32_to_bf16_v4(
    const float* __restrict__ s, u16* __restrict__ d, int n4) {
  int i = blockIdx.x * 256 + threadIdx.x;
  if (i >= n4) return;
  const float4 v = reinterpret_cast<const float4*>(s)[i];
  ushort4 o;
  o.x = f2bf(v.x);
  o.y = f2bf(v.y);
  o.z = f2bf(v.z);
  o.w = f2bf(v.w);
  reinterpret_cast<ushort4*>(d)[i] = o;
}

// ---------------- C = A @ B^T : A (MxK) bf16, B (NxK) bf16 -----------------
// 128x128 tile, BK=64, 4 waves (2x2, each 64x64), 16x16x32 bf16 MFMA.
// m97-style 2-phase: global_load_lds stage -> barrier -> MFMA -> barrier.
template <int OUT_F32>
__global__ __launch_bounds__(256, 2) void gemm_bt(
    const u16* __restrict__ A, const u16* __restrict__ B,
    void* __restrict__ Cout, int M, int N, int K) {
  __shared__ u16 sA[128 * 64];
  __shared__ u16 sB[128 * 64];
  const int tid = threadIdx.x;
  const int lane = tid & 63;
  const int wid = tid >> 6;
  const int m0 = blockIdx.y * 128;
  const int n0 = blockIdx.x * 128;
  const int wr = wid >> 1, wc = wid & 1;

  f32x4 acc[4][4];
#pragma unroll
  for (int i = 0; i < 4; ++i)
#pragma unroll
    for (int j = 0; j < 4; ++j) acc[i][j] = {0.f, 0.f, 0.f, 0.f};

  const int nK = K >> 6;  // K / 64
  for (int kt = 0; kt < nK; ++kt) {
    const u16* Ag = A + (size_t)m0 * K + kt * 64;
    const u16* Bg = B + (size_t)n0 * K + kt * 64;
    // stage A tile [128][64] bf16 (16 KiB), linear row-major; wave-uniform LDS
    // base + lane*16 (global_load_lds hardware layout).
#pragma unroll
    for (int it = 0; it < 4; ++it) {
      const int o = (it * 256 + tid) * 16;  // byte offset in tile
      const int row = o >> 7;               // 128 B per row
      const int colb = o & 127;
      GLD_LDS16((const char*)(Ag + (size_t)row * K) + colb,
                (char*)sA + it * 4096 + wid * 1024);
    }
#pragma unroll
    for (int it = 0; it < 4; ++it) {
      const int o = (it * 256 + tid) * 16;
      const int row = o >> 7;
      const int colb = o & 127;
      GLD_LDS16((const char*)(Bg + (size_t)row * K) + colb,
                (char*)sB + it * 4096 + wid * 1024);
    }
    __syncthreads();  // compiler emits vmcnt(0) drain before s_barrier

#pragma unroll
    for (int kk = 0; kk < 2; ++kk) {
      short8 af[4], bfr[4];
      const int col = kk * 32 + (lane >> 4) * 8;  // k-offset of this lane
#pragma unroll
      for (int f = 0; f < 4; ++f) {
        const int ra = wr * 64 + f * 16 + (lane & 15);
        af[f] = *reinterpret_cast<const short8*>(&sA[ra * 64 + col]);
        const int rb = wc * 64 + f * 16 + (lane & 15);
        bfr[f] = *reinterpret_cast<const short8*>(&sB[rb * 64 + col]);
      }
#pragma unroll
      for (int i = 0; i < 4; ++i)
#pragma unroll
        for (int j = 0; j < 4; ++j)
          acc[i][j] = __builtin_amdgcn_mfma_f32_16x16x32_bf16(
              af[i], bfr[j], acc[i][j], 0, 0, 0);
    }
    __syncthreads();
  }

  // Epilogue. C/D layout: col = lane&15, row = (lane>>4)*4 + e  [m89/m91].
  const int rbase = m0 + wr * 64 + ((lane >> 4) << 2);
  const int cbase = n0 + wc * 64 + (lane & 15);
  if (OUT_F32) {
    float* C = (float*)Cout;
#pragma unroll
    for (int i = 0; i < 4; ++i)
#pragma unroll
      for (int j = 0; j < 4; ++j)
#pragma unroll
        for (int e = 0; e < 4; ++e)
          C[(size_t)(rbase + i * 16 + e) * N + (cbase + j * 16)] =
              acc[i][j][e];
  } else {
    u16* C = (u16*)Cout;
#pragma unroll
    for (int i = 0; i < 4; ++i)
#pragma unroll
      for (int j = 0; j < 4; ++j)
#pragma unroll
        for (int e = 0; e < 4; ++e)
          C[(size_t)(rbase + i * 16 + e) * N + (cbase + j * 16)] =
              f2bf(acc[i][j][e]);
  }
}

// ---------------- RoPE + head-mix attention, one block per token -----------
__global__ __launch_bounds__(256) void rope_attn(
    const u16* __restrict__ qkv, u16* __restrict__ attn, int S) {
  __shared__ float cosv[64], sinv[64];
  __shared__ float sq[16][132];  // +4 pad: kills 16-way bank conflict on dot
  __shared__ float sk[16][132];
  __shared__ float sp[16][16];
  const int token = blockIdx.x;
  const int s = token & (S - 1);  // S = 4096 (pow2); position in sequence
  const int tid = threadIdx.x;
  const u16* base = qkv + (size_t)token * 6144;

  if (tid < 64) {
    const float inv = powf(10000.0f, -(float)tid * (1.0f / 64.0f));
    float sv, cv;
    sincosf((float)s * inv, &sv, &cv);
    cosv[tid] = cv;
    sinv[tid] = sv;
  }
  __syncthreads();

  // RoPE q and k into LDS (f32). 2048 pairs total, 8 per thread.
#pragma unroll
  for (int p = 0; p < 8; ++p) {
    const int idx = p * 256 + tid;  // 0..2047
    const int mat = idx >> 10;      // 0 = q, 1 = k
    const int rem = idx & 1023;
    const int h = rem >> 6;
    const int i = rem & 63;
    const u16* src = base + mat * 2048 + h * 128 + 2 * i;
    const float x1 = bf2f(src[0]);
    const float x2 = bf2f(src[1]);
    const float c = cosv[i], sn = sinv[i];
    float* dst = mat ? sk[h] : sq[h];
    dst[2 * i] = x1 * c - x2 * sn;
    dst[2 * i + 1] = x1 * sn + x2 * c;
  }
  __syncthreads();

  // scores + softmax: one thread per (h, t); q-head permutation folded here.
  {
    const int h = tid >> 4;
    const int t = tid & 15;
    const int hp = ((h & 3) << 2) | (h >> 2);  // original head feeding new h
    float sc = 0.f;
#pragma unroll
    for (int d = 0; d < 128; ++d) sc += sq[hp][d] * sk[t][d];
    sc *= 0.08838834764831845f;  // 1/sqrt(128)
    float mx = sc;
#pragma unroll
    for (int o = 8; o; o >>= 1) mx = fmaxf(mx, __shfl_xor(mx, o, 16));
    const float e = __expf(sc - mx);
    float sum = e;
#pragma unroll
    for (int o = 8; o; o >>= 1) sum += __shfl_xor(sum, o, 16);
    sp[h][t] = e / sum;
  }
  __syncthreads();

  // PV: thread owns (h, 8 consecutive d); v read direct from global (L2-hot).
  {
    const int h = tid >> 4;
    const int d0 = (tid & 15) * 8;
    const u16* vb = base + 4096;
    float o[8] = {0.f, 0.f, 0.f, 0.f, 0.f, 0.f, 0.f, 0.f};
#pragma unroll
    for (int t = 0; t < 16; ++t) {
      const float pr = sp[h][t];
      const short8 vv = *reinterpret_cast<const short8*>(vb + t * 128 + d0);
#pragma unroll
      for (int e = 0; e < 8; ++e) o[e] += pr * bf2f((u16)vv[e]);
    }
    short8 ov;
#pragma unroll
    for (int e = 0; e < 8; ++e) ov[e] = (short)f2bf(o[e]);
    *reinterpret_cast<short8*>(attn + (size_t)token * 2048 + h * 128 + d0) =
        ov;
  }
}

// ---------------------------------------------------------------------------
extern "C" void kernel_launch(void* const* d_in, const int* in_sizes, int n_in,
                              void* d_out, int out_size, void* d_ws,
                              size_t ws_size, hipStream_t stream) {
  (void)in_sizes;
  (void)n_in;
  (void)out_size;
  (void)ws_size;
  const float* x = (const float*)d_in[0];
  const float* Wq = (const float*)d_in[1];
  const float* Wk = (const float*)d_in[2];
  const float* Wv = (const float*)d_in[3];
  const float* Wo = (const float*)d_in[4];
  float* out = (float*)d_out;

  const int B = 4, S = 4096, D = 2048;
  const int M = B * S;  // 16384

  char* ws = (char*)d_ws;
  u16* xb = (u16*)ws;                               // M*D bf16; reused as attn
  u16* wqkv = (u16*)(ws + (size_t)M * D * 2);       // 3*D*D bf16
  u16* wo = (u16*)((char*)wqkv + (size_t)3 * D * D * 2);
  u16* qkv = (u16*)((char*)wo + (size_t)D * D * 2);  // M*3D bf16

  // bf16 conversions
  cvt_f32_to_bf16_v4<<<(M * D / 4 + 255) / 256, 256, 0, stream>>>(x, xb,
                                                                  M * D / 4);
  const int w4 = D * D / 4;
  cvt_f32_to_bf16_v4<<<(w4 + 255) / 256, 256, 0, stream>>>(Wq, wqkv, w4);
  cvt_f32_to_bf16_v4<<<(w4 + 255) / 256, 256, 0, stream>>>(
      Wk, wqkv + (size_t)D * D, w4);
  cvt_f32_to_bf16_v4<<<(w4 + 255) / 256, 256, 0, stream>>>(
      Wv, wqkv + (size_t)2 * D * D, w4);
  cvt_f32_to_bf16_v4<<<(w4 + 255) / 256, 256, 0, stream>>>(Wo, wo, w4);

  // qkv = x @ [Wq;Wk;Wv]^T   (M x 3D, bf16 out)
  gemm_bt<0><<<dim3(3 * D / 128, M / 128), 256, 0, stream>>>(xb, wqkv, qkv, M,
                                                             3 * D, D);
  // RoPE + per-token head attention -> attn (reuses xb)
  rope_attn<<<M, 256, 0, stream>>>(qkv, xb, S);
  // out = attn @ Wo^T (f32 out)
  gemm_bt<1><<<dim3(D / 128, M / 128), 256, 0, stream>>>(xb, wo, out, M, D, D);
}